// Round 4
// baseline (131.682 us; speedup 1.0000x reference)
//
#include <hip/hip_runtime.h>
#include <hip/hip_bf16.h>

#define NN 50000
#define NE 800000
#define C 128
#define HH 64
#define TIN 288
#define LN_EPS 1e-5f

typedef __attribute__((ext_vector_type(8))) short bf16x8;
typedef __attribute__((ext_vector_type(4))) float f32x4;

// ws layout (bytes):
//   [0,256)           sj[64] f32
//   [256,512)         cj[64] f32
//   [512,37376)       B1frag: [kt=9][nt=4][lane=64][j=8] bf16 (36864 B)
//   [37376,39424)     B2frag: [kt=2][lane=64][j=8] bf16       (2048 B)
//   [39424,239424)    S[50000] f32
//   [239424,439424)   Q[50000] f32
//   [439424,...)      x_bf[50000][128] bf16 (if ws fits)
#define S_OFF 39424
#define Q_OFF 239424
#define XBF_OFF 439424
#define WS_NEED (XBF_OFF + (size_t)NN * C * 2)

__device__ __forceinline__ short f2bf(float f) {
    __hip_bfloat16 h = __float2bfloat16(f);
    return __builtin_bit_cast(short, h);
}

__global__ void prep_weights(const float* __restrict__ ln_w,
                             const float* __restrict__ ln_b,
                             const float* __restrict__ W1,
                             const float* __restrict__ b1,
                             const float* __restrict__ W2,
                             float* __restrict__ ws) {
    int tid = threadIdx.x;  // 256
    if (tid < 64) {
        int l = tid;
        float s = 0.f, c = 0.f;
        for (int k = 0; k < TIN; ++k) {
            float w = W1[k * HH + l];
            s += ln_w[k] * w;
            c += ln_b[k] * w;
        }
        ws[l] = s;
        ws[64 + l] = c + b1[l];
    }
    short* B1 = (short*)((char*)ws + 512);
    for (int idx = tid; idx < 18432; idx += 256) {
        int j = idx & 7, l = (idx >> 3) & 63, nt = (idx >> 9) & 3, kt = idx >> 11;
        int g = l >> 4, m = l & 15;
        int k = 32 * kt + 8 * g + j, n = 16 * nt + m;
        B1[idx] = f2bf(ln_w[k] * W1[k * HH + n]);
    }
    short* B2 = B1 + 18432;
    for (int idx = tid; idx < 1024; idx += 256) {
        int j = idx & 7, l = (idx >> 3) & 63, kt = idx >> 9;
        int g = l >> 4, m = l & 15;
        int k = 32 * kt + 8 * g + j;
        B2[idx] = f2bf(W2[k * 16 + m]);
    }
}

__global__ void prep_nodes(const float* __restrict__ x,
                           float* __restrict__ S,
                           float* __restrict__ Q,
                           unsigned short* __restrict__ x_bf) {
    int n = blockIdx.x * 4 + (threadIdx.x >> 6);
    if (n >= NN) return;
    int l = threadIdx.x & 63;
    float2 v = *(const float2*)(x + (size_t)n * C + 2 * l);
    if (x_bf) {
        ushort2 o;
        o.x = (unsigned short)f2bf(v.x);
        o.y = (unsigned short)f2bf(v.y);
        *(ushort2*)(x_bf + (size_t)n * C + 2 * l) = o;
    }
    float s = v.x + v.y;
    float q = v.x * v.x + v.y * v.y;
#pragma unroll
    for (int d = 1; d < 64; d <<= 1) {
        s += __shfl_xor(s, d);
        q += __shfl_xor(q, d);
    }
    if (l == 0) { S[n] = s; Q[n] = q; }
}

template <bool XBF>
__global__ __launch_bounds__(256, 3) void edge_kernel(
    const void* __restrict__ xv,
    const int* __restrict__ ei,
    const int* __restrict__ etype,
    const int* __restrict__ ntype,
    const float* __restrict__ ws,
    const float* __restrict__ S,
    const float* __restrict__ Q,
    const float* __restrict__ b2,
    float* __restrict__ out) {
    // LDS: B1 [0,18432) shorts | B2 [18432,19456).
    // hT (4 waves * 1024 shorts) aliases B1[0,4096) after GEMM1's barrier.
    __shared__ __align__(16) short lds_s[19456];

    int tid = threadIdx.x;
    {
        const float4* src = (const float4*)((const char*)ws + 512);
        float4* dst = (float4*)lds_s;
        for (int i = tid; i < 2432; i += 256) dst[i] = src[i];
    }
    __syncthreads();

    int wave = tid >> 6, lane = tid & 63;
    int m = lane & 15, g = lane >> 4;
    int ebase = blockIdx.x * 256 + wave * 64;  // 4 tiles of 16 edges

    int row[4], col[4];
#pragma unroll
    for (int t = 0; t < 4; ++t) {
        int e = ebase + 16 * t + m;
        row[t] = ei[e];
        col[t] = ei[NE + e];
    }
    int sel[4];
    float mu[4], rs[4];
#pragma unroll
    for (int t = 0; t < 4; ++t) {
        int e = ebase + 16 * t + m;
        int ntr = ntype[row[t]], ntc = ntype[col[t]], et = etype[e];
        sel[t] = (g == 0) ? ntr : (g == 1) ? ntc : (g == 2) ? et : (et - 8);
        float sum = S[row[t]] + S[col[t]] + 3.0f;
        float sq  = Q[row[t]] + Q[col[t]] + 3.0f;
        float mu_ = sum * (1.0f / TIN);
        mu[t] = mu_;
        rs[t] = rsqrtf(sq * (1.0f / TIN) - mu_ * mu_ + LN_EPS);
    }

    f32x4 acc[4][4];
#pragma unroll
    for (int t = 0; t < 4; ++t)
#pragma unroll
        for (int nt = 0; nt < 4; ++nt) acc[t][nt] = (f32x4){0.f, 0.f, 0.f, 0.f};

    if constexpr (XBF) {
        const unsigned short* xb = (const unsigned short*)xv;
        const unsigned short* pr[4];
        const unsigned short* pc[4];
#pragma unroll
        for (int t = 0; t < 4; ++t) {
            pr[t] = xb + (size_t)row[t] * C + g * 8;
            pc[t] = xb + (size_t)col[t] * C + g * 8;
        }
        // depth-2 software pipeline on the gathers
        bf16x8 pf0[4], pf1[4];
#pragma unroll
        for (int t = 0; t < 4; ++t) pf0[t] = *(const bf16x8*)(pr[t]);
#pragma unroll
        for (int t = 0; t < 4; ++t) pf1[t] = *(const bf16x8*)(pr[t] + 32);
#pragma unroll
        for (int kt = 0; kt < 8; ++kt) {
            bf16x8 a[4];
#pragma unroll
            for (int t = 0; t < 4; ++t) a[t] = (kt & 1) ? pf1[t] : pf0[t];
            if (kt < 6) {
                int k2 = kt + 2;
#pragma unroll
                for (int t = 0; t < 4; ++t) {
                    const unsigned short* p = (k2 < 4 ? pr[t] : pc[t]) + (k2 & 3) * 32;
                    if (kt & 1) pf1[t] = *(const bf16x8*)p;
                    else        pf0[t] = *(const bf16x8*)p;
                }
            }
            const bf16x8* Bk = (const bf16x8*)(lds_s + kt * 2048);
            bf16x8 b0 = Bk[lane], b1 = Bk[64 + lane], b2f = Bk[128 + lane], b3 = Bk[192 + lane];
#pragma unroll
            for (int t = 0; t < 4; ++t) {
                acc[t][0] = __builtin_amdgcn_mfma_f32_16x16x32_bf16(a[t], b0, acc[t][0], 0, 0, 0);
                acc[t][1] = __builtin_amdgcn_mfma_f32_16x16x32_bf16(a[t], b1, acc[t][1], 0, 0, 0);
                acc[t][2] = __builtin_amdgcn_mfma_f32_16x16x32_bf16(a[t], b2f, acc[t][2], 0, 0, 0);
                acc[t][3] = __builtin_amdgcn_mfma_f32_16x16x32_bf16(a[t], b3, acc[t][3], 0, 0, 0);
            }
        }
    } else {
        const float* xf = (const float*)xv;
#pragma unroll
        for (int kt = 0; kt < 8; ++kt) {
            const bf16x8* Bk = (const bf16x8*)(lds_s + kt * 2048);
            bf16x8 b0 = Bk[lane], b1 = Bk[64 + lane], b2f = Bk[128 + lane], b3 = Bk[192 + lane];
#pragma unroll
            for (int t = 0; t < 4; ++t) {
                const float* base = xf + (size_t)(kt < 4 ? row[t] : col[t]) * C +
                                    (kt & 3) * 32 + g * 8;
                float4 p0 = *(const float4*)base;
                float4 p1 = *(const float4*)(base + 4);
                bf16x8 a;
                a[0] = f2bf(p0.x); a[1] = f2bf(p0.y); a[2] = f2bf(p0.z); a[3] = f2bf(p0.w);
                a[4] = f2bf(p1.x); a[5] = f2bf(p1.y); a[6] = f2bf(p1.z); a[7] = f2bf(p1.w);
                acc[t][0] = __builtin_amdgcn_mfma_f32_16x16x32_bf16(a, b0, acc[t][0], 0, 0, 0);
                acc[t][1] = __builtin_amdgcn_mfma_f32_16x16x32_bf16(a, b1, acc[t][1], 0, 0, 0);
                acc[t][2] = __builtin_amdgcn_mfma_f32_16x16x32_bf16(a, b2f, acc[t][2], 0, 0, 0);
                acc[t][3] = __builtin_amdgcn_mfma_f32_16x16x32_bf16(a, b3, acc[t][3], 0, 0, 0);
            }
        }
    }

    {   // one-hot K-tile (kt = 8)
        const bf16x8* Bk = (const bf16x8*)(lds_s + 8 * 2048);
        bf16x8 b0 = Bk[lane], b1 = Bk[64 + lane], b2f = Bk[128 + lane], b3 = Bk[192 + lane];
#pragma unroll
        for (int t = 0; t < 4; ++t) {
            bf16x8 af;
#pragma unroll
            for (int j = 0; j < 8; ++j) af[j] = (j == sel[t]) ? (short)0x3F80 : (short)0;
            acc[t][0] = __builtin_amdgcn_mfma_f32_16x16x32_bf16(af, b0, acc[t][0], 0, 0, 0);
            acc[t][1] = __builtin_amdgcn_mfma_f32_16x16x32_bf16(af, b1, acc[t][1], 0, 0, 0);
            acc[t][2] = __builtin_amdgcn_mfma_f32_16x16x32_bf16(af, b2f, acc[t][2], 0, 0, 0);
            acc[t][3] = __builtin_amdgcn_mfma_f32_16x16x32_bf16(af, b3, acc[t][3], 0, 0, 0);
        }
    }

    // hoisted epilogue constants
    float sjv[4], cjv[4];
#pragma unroll
    for (int nt = 0; nt < 4; ++nt) {
        sjv[nt] = ws[16 * nt + m];
        cjv[nt] = ws[64 + 16 * nt + m];
    }
    const bf16x8* B2f = (const bf16x8*)(lds_s + 18432);
    bf16x8 w20 = B2f[lane], w21 = B2f[64 + lane];
    float b2v = b2[m];

    __syncthreads();  // all waves done reading B1 -> hT may overlay it

    short* hTw = lds_s + wave * 1024;
    int r4 = m >> 2, c4 = m & 3;
    float diag = (c4 == r4) ? 1.0f : 0.0f;

#pragma unroll
    for (int t = 0; t < 4; ++t) {
        float muv[4], rsv[4];
#pragma unroll
        for (int i = 0; i < 4; ++i) {
            muv[i] = __shfl(mu[t], 4 * g + i);
            rsv[i] = __shfl(rs[t], 4 * g + i);
        }
#pragma unroll
        for (int nt = 0; nt < 4; ++nt)
#pragma unroll
            for (int i = 0; i < 4; ++i) {
                float hv = rsv[i] * (acc[t][nt][i] - muv[i] * sjv[nt]) + cjv[nt];
                hv = fmaxf(hv, 0.0f);
                int erow = 4 * g + i;
                int sidx = (erow * 64 + 16 * nt + m) ^ ((erow & 7) << 3);
                hTw[sidx] = f2bf(hv);
            }
        // GEMM2 (same-wave RAW through LDS; compiler orders via lgkmcnt)
        f32x4 o = {0.f, 0.f, 0.f, 0.f};
        {
            int sb0 = (m * 64 + 0  + 8 * g) ^ ((m & 7) << 3);
            int sb1 = (m * 64 + 32 + 8 * g) ^ ((m & 7) << 3);
            bf16x8 a0 = *(const bf16x8*)(hTw + sb0);
            bf16x8 a1 = *(const bf16x8*)(hTw + sb1);
            o = __builtin_amdgcn_mfma_f32_16x16x32_bf16(a0, w20, o, 0, 0, 0);
            o = __builtin_amdgcn_mfma_f32_16x16x32_bf16(a1, w21, o, 0, 0, 0);
        }
#pragma unroll
        for (int i = 0; i < 4; ++i) {
            float v = o[i] + b2v;
            float mx = fmaxf(v, __shfl_xor(v, 1));
            mx = fmaxf(mx, __shfl_xor(mx, 2));
            float ev = __expf(v - mx);
            float sd = ev + __shfl_xor(ev, 1);
            sd += __shfl_xor(sd, 2);
            out[(size_t)(ebase + 16 * t + 4 * g + i) * 16 + m] = diag - ev / sd;
        }
    }
}

extern "C" void kernel_launch(void* const* d_in, const int* in_sizes, int n_in,
                              void* d_out, int out_size, void* d_ws, size_t ws_size,
                              hipStream_t stream) {
    const float* x     = (const float*)d_in[0];
    const int*   ei    = (const int*)d_in[1];
    const int*   etype = (const int*)d_in[2];
    const int*   ntype = (const int*)d_in[3];
    const float* ln_w  = (const float*)d_in[4];
    const float* ln_b  = (const float*)d_in[5];
    const float* W1    = (const float*)d_in[6];
    const float* b1    = (const float*)d_in[7];
    const float* W2    = (const float*)d_in[8];
    const float* b2    = (const float*)d_in[9];
    float* out = (float*)d_out;
    float* ws  = (float*)d_ws;

    float* S = (float*)((char*)d_ws + S_OFF);
    float* Q = (float*)((char*)d_ws + Q_OFF);
    unsigned short* x_bf = (unsigned short*)((char*)d_ws + XBF_OFF);
    bool use_xbf = ws_size >= WS_NEED;

    prep_weights<<<1, 256, 0, stream>>>(ln_w, ln_b, W1, b1, W2, ws);
    prep_nodes<<<(NN + 3) / 4, 256, 0, stream>>>(x, S, Q, use_xbf ? x_bf : nullptr);

    int grid = NE / 256;  // 3125, exact
    if (use_xbf)
        edge_kernel<true><<<grid, 256, 0, stream>>>(x_bf, ei, etype, ntype, ws,
                                                    S, Q, b2, out);
    else
        edge_kernel<false><<<grid, 256, 0, stream>>>(x, ei, etype, ntype, ws,
                                                     S, Q, b2, out);
}

// Round 5
// 115.712 us; speedup vs baseline: 1.1380x; 1.1380x over previous
//
#include <hip/hip_runtime.h>
#include <hip/hip_bf16.h>

#define NN 50000
#define NE 800000
#define C 128
#define HH 64
#define TIN 288
#define LN_EPS 1e-5f

typedef __attribute__((ext_vector_type(8))) short bf16x8;
typedef __attribute__((ext_vector_type(4))) float f32x4;

// ws layout (bytes):
//   [0,256)           sj[64] f32
//   [256,512)         cj[64] f32
//   [512,37376)       B1frag: [kt=9][nt=4][lane=64][j=8] bf16 (36864 B)
//   [37376,39424)     B2frag: [kt=2][lane=64][j=8] bf16       (2048 B)
//   [39424,239424)    S[50000] f32
//   [239424,439424)   Q[50000] f32
//   [439424,...)      x_bf[50000][128] bf16 (if ws fits)
#define S_OFF 39424
#define Q_OFF 239424
#define XBF_OFF 439424
#define WS_NEED (XBF_OFF + (size_t)NN * C * 2)

__device__ __forceinline__ short f2bf(float f) {
    __hip_bfloat16 h = __float2bfloat16(f);
    return __builtin_bit_cast(short, h);
}

__global__ void prep_weights(const float* __restrict__ ln_w,
                             const float* __restrict__ ln_b,
                             const float* __restrict__ W1,
                             const float* __restrict__ b1,
                             const float* __restrict__ W2,
                             float* __restrict__ ws) {
    int tid = threadIdx.x;  // 256
    if (tid < 64) {
        int l = tid;
        float s = 0.f, c = 0.f;
        for (int k = 0; k < TIN; ++k) {
            float w = W1[k * HH + l];
            s += ln_w[k] * w;
            c += ln_b[k] * w;
        }
        ws[l] = s;
        ws[64 + l] = c + b1[l];
    }
    short* B1 = (short*)((char*)ws + 512);
    for (int idx = tid; idx < 18432; idx += 256) {
        int j = idx & 7, l = (idx >> 3) & 63, nt = (idx >> 9) & 3, kt = idx >> 11;
        int g = l >> 4, m = l & 15;
        int k = 32 * kt + 8 * g + j, n = 16 * nt + m;
        B1[idx] = f2bf(ln_w[k] * W1[k * HH + n]);
    }
    short* B2 = B1 + 18432;
    for (int idx = tid; idx < 1024; idx += 256) {
        int j = idx & 7, l = (idx >> 3) & 63, kt = idx >> 9;
        int g = l >> 4, m = l & 15;
        int k = 32 * kt + 8 * g + j;
        B2[idx] = f2bf(W2[k * 16 + m]);
    }
}

__global__ void prep_nodes(const float* __restrict__ x,
                           float* __restrict__ S,
                           float* __restrict__ Q,
                           unsigned short* __restrict__ x_bf) {
    int n = blockIdx.x * 4 + (threadIdx.x >> 6);
    if (n >= NN) return;
    int l = threadIdx.x & 63;
    float2 v = *(const float2*)(x + (size_t)n * C + 2 * l);
    if (x_bf) {
        ushort2 o;
        o.x = (unsigned short)f2bf(v.x);
        o.y = (unsigned short)f2bf(v.y);
        *(ushort2*)(x_bf + (size_t)n * C + 2 * l) = o;
    }
    float s = v.x + v.y;
    float q = v.x * v.x + v.y * v.y;
#pragma unroll
    for (int d = 1; d < 64; d <<= 1) {
        s += __shfl_xor(s, d);
        q += __shfl_xor(q, d);
    }
    if (l == 0) { S[n] = s; Q[n] = q; }
}

template <bool XBF>
__global__ __launch_bounds__(512, 6) void edge_kernel(
    const void* __restrict__ xv,
    const int* __restrict__ ei,
    const int* __restrict__ etype,
    const int* __restrict__ ntype,
    const float* __restrict__ ws,
    const float* __restrict__ S,
    const float* __restrict__ Q,
    const float* __restrict__ b2,
    float* __restrict__ out) {
    // LDS: B1 [0,18432) shorts | B2 [18432,19456).
    // hT (8 waves * 1024 shorts) aliases B1[0,8192) after GEMM1's barrier.
    __shared__ __align__(16) short lds_s[19456];

    int tid = threadIdx.x;
    {
        const float4* src = (const float4*)((const char*)ws + 512);
        float4* dst = (float4*)lds_s;
        for (int i = tid; i < 2432; i += 512) dst[i] = src[i];
    }
    __syncthreads();

    int wave = tid >> 6, lane = tid & 63;
    int m = lane & 15, g = lane >> 4;
    int tile = blockIdx.x * 128 + wave * 16;
    int e = tile + m;

    int row = ei[e];
    int col = ei[NE + e];
    int ntr = ntype[row], ntc = ntype[col], et = etype[e];
    int sel = (g == 0) ? ntr : (g == 1) ? ntc : (g == 2) ? et : (et - 8);

    float sum = S[row] + S[col] + 3.0f;
    float sumsq = Q[row] + Q[col] + 3.0f;
    float mu = sum * (1.0f / TIN);
    float var = sumsq * (1.0f / TIN) - mu * mu;
    float rstd = rsqrtf(var + LN_EPS);

    // ---- issue ALL 8 gather loads upfront (latency hiding via in-flight depth)
    bf16x8 a0, a1, a2, a3, a4, a5, a6, a7, a8;
    if constexpr (XBF) {
        const unsigned short* xb = (const unsigned short*)xv;
        const unsigned short* pr = xb + (size_t)row * C + g * 8;
        const unsigned short* pc = xb + (size_t)col * C + g * 8;
        a0 = *(const bf16x8*)(pr);
        a1 = *(const bf16x8*)(pr + 32);
        a2 = *(const bf16x8*)(pr + 64);
        a3 = *(const bf16x8*)(pr + 96);
        a4 = *(const bf16x8*)(pc);
        a5 = *(const bf16x8*)(pc + 32);
        a6 = *(const bf16x8*)(pc + 64);
        a7 = *(const bf16x8*)(pc + 96);
    } else {
        const float* xf = (const float*)xv;
        const float* pr = xf + (size_t)row * C + g * 8;
        const float* pc = xf + (size_t)col * C + g * 8;
#pragma unroll
        for (int q = 0; q < 8; ++q) {
            const float* p = (q < 4 ? pr : pc) + (q & 3) * 32;
            float4 p0 = *(const float4*)p;
            float4 p1 = *(const float4*)(p + 4);
            bf16x8 a;
            a[0] = f2bf(p0.x); a[1] = f2bf(p0.y); a[2] = f2bf(p0.z); a[3] = f2bf(p0.w);
            a[4] = f2bf(p1.x); a[5] = f2bf(p1.y); a[6] = f2bf(p1.z); a[7] = f2bf(p1.w);
            switch (q) {
                case 0: a0 = a; break; case 1: a1 = a; break;
                case 2: a2 = a; break; case 3: a3 = a; break;
                case 4: a4 = a; break; case 5: a5 = a; break;
                case 6: a6 = a; break; default: a7 = a; break;
            }
        }
    }
#pragma unroll
    for (int j = 0; j < 8; ++j) a8[j] = (j == sel) ? (short)0x3F80 : (short)0;

    f32x4 acc0 = {0.f, 0.f, 0.f, 0.f};
    f32x4 acc1 = {0.f, 0.f, 0.f, 0.f};
    f32x4 acc2 = {0.f, 0.f, 0.f, 0.f};
    f32x4 acc3 = {0.f, 0.f, 0.f, 0.f};

    bf16x8 afr[9] = {a0, a1, a2, a3, a4, a5, a6, a7, a8};
#pragma unroll
    for (int kt = 0; kt < 9; ++kt) {
        const bf16x8* Bk = (const bf16x8*)(lds_s + kt * 2048);
        bf16x8 b0 = Bk[lane], b1 = Bk[64 + lane], b2f = Bk[128 + lane], b3 = Bk[192 + lane];
        acc0 = __builtin_amdgcn_mfma_f32_16x16x32_bf16(afr[kt], b0, acc0, 0, 0, 0);
        acc1 = __builtin_amdgcn_mfma_f32_16x16x32_bf16(afr[kt], b1, acc1, 0, 0, 0);
        acc2 = __builtin_amdgcn_mfma_f32_16x16x32_bf16(afr[kt], b2f, acc2, 0, 0, 0);
        acc3 = __builtin_amdgcn_mfma_f32_16x16x32_bf16(afr[kt], b3, acc3, 0, 0, 0);
    }

    // per-row LN stats for the 4 C-rows this lane holds (edges 4g+i)
    float muv[4], rsv[4];
#pragma unroll
    for (int i = 0; i < 4; ++i) {
        muv[i] = __shfl(mu, 4 * g + i);
        rsv[i] = __shfl(rstd, 4 * g + i);
    }
    float sjv[4], cjv[4];
#pragma unroll
    for (int nt = 0; nt < 4; ++nt) {
        sjv[nt] = ws[16 * nt + m];
        cjv[nt] = ws[64 + 16 * nt + m];
    }
    const bf16x8* B2f = (const bf16x8*)(lds_s + 18432);
    bf16x8 w20 = B2f[lane], w21 = B2f[64 + lane];
    float b2v = b2[m];

    __syncthreads();  // all waves done reading B1 -> hT may overlay it

    // hid = relu(rstd*(G - mu*s) + c) -> bf16 -> swizzled LDS transpose
    short* hTw = lds_s + wave * 1024;
    f32x4 accs[4] = {acc0, acc1, acc2, acc3};
#pragma unroll
    for (int nt = 0; nt < 4; ++nt) {
#pragma unroll
        for (int i = 0; i < 4; ++i) {
            float hv = rsv[i] * (accs[nt][i] - muv[i] * sjv[nt]) + cjv[nt];
            hv = fmaxf(hv, 0.0f);
            int erow = 4 * g + i;
            int sidx = (erow * 64 + 16 * nt + m) ^ ((erow & 7) << 3);
            hTw[sidx] = f2bf(hv);
        }
    }
    // wave reads only its own hT slice -> same-wave RAW ordered by lgkmcnt

    f32x4 o = {0.f, 0.f, 0.f, 0.f};
    {
        int sb0 = (m * 64 + 0 + 8 * g) ^ ((m & 7) << 3);
        int sb1 = (m * 64 + 32 + 8 * g) ^ ((m & 7) << 3);
        bf16x8 q0 = *(const bf16x8*)(hTw + sb0);
        bf16x8 q1 = *(const bf16x8*)(hTw + sb1);
        o = __builtin_amdgcn_mfma_f32_16x16x32_bf16(q0, w20, o, 0, 0, 0);
        o = __builtin_amdgcn_mfma_f32_16x16x32_bf16(q1, w21, o, 0, 0, 0);
    }

    int r4 = m >> 2, c4 = m & 3;
    float diag = (c4 == r4) ? 1.0f : 0.0f;
#pragma unroll
    for (int i = 0; i < 4; ++i) {
        float v = o[i] + b2v;
        float mx = fmaxf(v, __shfl_xor(v, 1));
        mx = fmaxf(mx, __shfl_xor(mx, 2));
        float ev = __expf(v - mx);
        float sd = ev + __shfl_xor(ev, 1);
        sd += __shfl_xor(sd, 2);
        out[(size_t)(tile + 4 * g + i) * 16 + m] = diag - ev / sd;
    }
}

extern "C" void kernel_launch(void* const* d_in, const int* in_sizes, int n_in,
                              void* d_out, int out_size, void* d_ws, size_t ws_size,
                              hipStream_t stream) {
    const float* x     = (const float*)d_in[0];
    const int*   ei    = (const int*)d_in[1];
    const int*   etype = (const int*)d_in[2];
    const int*   ntype = (const int*)d_in[3];
    const float* ln_w  = (const float*)d_in[4];
    const float* ln_b  = (const float*)d_in[5];
    const float* W1    = (const float*)d_in[6];
    const float* b1    = (const float*)d_in[7];
    const float* W2    = (const float*)d_in[8];
    const float* b2    = (const float*)d_in[9];
    float* out = (float*)d_out;
    float* ws  = (float*)d_ws;

    float* S = (float*)((char*)d_ws + S_OFF);
    float* Q = (float*)((char*)d_ws + Q_OFF);
    unsigned short* x_bf = (unsigned short*)((char*)d_ws + XBF_OFF);
    bool use_xbf = ws_size >= WS_NEED;

    prep_weights<<<1, 256, 0, stream>>>(ln_w, ln_b, W1, b1, W2, ws);
    prep_nodes<<<(NN + 3) / 4, 256, 0, stream>>>(x, S, Q, use_xbf ? x_bf : nullptr);

    int grid = NE / 128;  // 6250, exact
    if (use_xbf)
        edge_kernel<true><<<grid, 512, 0, stream>>>(x_bf, ei, etype, ntype, ws,
                                                    S, Q, b2, out);
    else
        edge_kernel<false><<<grid, 512, 0, stream>>>(x, ei, etype, ntype, ws,
                                                     S, Q, b2, out);
}

// Round 6
// 78.424 us; speedup vs baseline: 1.6791x; 1.4755x over previous
//
#include <hip/hip_runtime.h>
#include <hip/hip_bf16.h>

#define NN 50000
#define NE 800000
#define C 128
#define HH 64
#define TIN 288
#define LN_EPS 1e-5f

typedef __attribute__((ext_vector_type(8))) short bf16x8;
typedef __attribute__((ext_vector_type(4))) float f32x4;

// ws layout (bytes) — total 13,239,424 (== previously confirmed available)
//   [0,256)             s[64] f32   (column sums of W1p, all 288 rows)
//   [256,512)           c[64] f32   (ln_b·W1 + b1)
//   [512,2560)          et_tab [16][64] bf16, XOR-swizzled 16B units
//   [2560,35328)        B1frag: [kt=8][c=4][lane=64][j=8] bf16 (32768 B)
//   [35328,37376)       B2frag: [kt=2][lane=64][j=8] bf16 (2048 B)
//   [37376,38400)       ohu [8][64] bf16  (W1p rows 256..263)
//   [38400,39424)       ohv [8][64] bf16  (W1p rows 264..271)
//   [39424,439424)      SQ float2[50000]  (per-node sum, sumsq of f32 x)
//   [439424,6839424)    u bf16[50000][64]
//   [6839424,13239424)  v bf16[50000][64]
#define ETT_OFF 512
#define B1F_OFF 2560
#define B2F_OFF 35328
#define OHU_OFF 37376
#define OHV_OFF 38400
#define SQ_OFF 39424
#define U_OFF 439424
#define V_OFF 6839424

__device__ __forceinline__ short f2bf(float f) {
    __hip_bfloat16 h = __float2bfloat16(f);
    return __builtin_bit_cast(short, h);
}
__device__ __forceinline__ float bf2f(short s) {
    unsigned int u = ((unsigned int)(unsigned short)s) << 16;
    return __builtin_bit_cast(float, u);
}

__global__ void prep_weights(const float* __restrict__ ln_w,
                             const float* __restrict__ ln_b,
                             const float* __restrict__ W1,
                             const float* __restrict__ b1,
                             const float* __restrict__ W2,
                             float* __restrict__ ws) {
    int gid = blockIdx.x * 256 + threadIdx.x;  // 32 blocks x 256
    if (blockIdx.x == 0 && threadIdx.x < 64) {
        int l = threadIdx.x;
        float s = 0.f, c = 0.f;
        for (int k = 0; k < TIN; ++k) {
            float w = W1[k * HH + l];
            s += ln_w[k] * w;
            c += ln_b[k] * w;
        }
        ws[l] = s;
        ws[64 + l] = c + b1[l];
    }
    short* B1 = (short*)((char*)ws + B1F_OFF);
    for (int idx = gid; idx < 16384; idx += 8192) {
        int j = idx & 7, l = (idx >> 3) & 63, cc = (idx >> 9) & 3, kt = idx >> 11;
        int g = l >> 4, m = l & 15;
        int k = 32 * kt + 8 * g + j, n = 16 * cc + m;
        B1[idx] = f2bf(ln_w[k] * W1[k * HH + n]);
    }
    short* B2 = (short*)((char*)ws + B2F_OFF);
    for (int idx = gid; idx < 1024; idx += 8192) {
        int j = idx & 7, l = (idx >> 3) & 63, kt = idx >> 9;
        int g = l >> 4, m = l & 15;
        int k = 32 * kt + 8 * g + j;
        B2[idx] = f2bf(W2[k * 16 + m]);
    }
    short* ohu = (short*)((char*)ws + OHU_OFF);
    short* ohv = (short*)((char*)ws + OHV_OFF);
    for (int idx = gid; idx < 512; idx += 8192) {
        int t = idx >> 6, j = idx & 63;
        ohu[idx] = f2bf(ln_w[256 + t] * W1[(256 + t) * HH + j]);
        ohv[idx] = f2bf(ln_w[264 + t] * W1[(264 + t) * HH + j]);
    }
    short* ett = (short*)((char*)ws + ETT_OFF);
    for (int idx = gid; idx < 1024; idx += 8192) {
        int et = idx >> 6, j = idx & 63;
        int unit = (j >> 3) ^ (et & 7);  // bank-conflict swizzle on 16B units
        ett[et * 64 + unit * 8 + (j & 7)] = f2bf(ln_w[272 + et] * W1[(272 + et) * HH + j]);
    }
}

// per-node: u = x·W1p[0:128] + ohu[ntype], v = x·W1p[128:256] + ohv[ntype],
// plus SQ = (sum, sumsq) of f32 x row.
__global__ __launch_bounds__(512) void node_uv(const float* __restrict__ x,
                                               const int* __restrict__ ntype,
                                               float* __restrict__ ws) {
    __shared__ __align__(16) short lds_n[16384 + 8 * 1024];
    int tid = threadIdx.x;
    {
        const float4* src = (const float4*)((const char*)ws + B1F_OFF);
        float4* dst = (float4*)lds_n;
        for (int i = tid; i < 2048; i += 512) dst[i] = src[i];
    }
    __syncthreads();

    int wave = tid >> 6, lane = tid & 63, m = lane & 15, g = lane >> 4;
    int tile = blockIdx.x * 128 + wave * 16;
    int n = tile + m;
    int nc = n < NN ? n : NN - 1;

    float sum = 0.f, sq = 0.f;
    bf16x8 a[4];
#pragma unroll
    for (int kt = 0; kt < 4; ++kt) {
        const float* p = x + (size_t)nc * C + kt * 32 + g * 8;
        float4 p0 = *(const float4*)p;
        float4 p1 = *(const float4*)(p + 4);
        float vv[8] = {p0.x, p0.y, p0.z, p0.w, p1.x, p1.y, p1.z, p1.w};
#pragma unroll
        for (int j = 0; j < 8; ++j) {
            sum += vv[j];
            sq = fmaf(vv[j], vv[j], sq);
            a[kt][j] = f2bf(vv[j]);
        }
    }
    // reduce S,Q across g-groups (lanes sharing m)
    sum += __shfl_xor(sum, 16); sum += __shfl_xor(sum, 32);
    sq  += __shfl_xor(sq, 16);  sq  += __shfl_xor(sq, 32);
    if (g == 0 && n < NN)
        ((float2*)((char*)ws + SQ_OFF))[n] = make_float2(sum, sq);

    f32x4 au[4], av[4];
#pragma unroll
    for (int cc = 0; cc < 4; ++cc) { au[cc] = (f32x4){0,0,0,0}; av[cc] = (f32x4){0,0,0,0}; }
#pragma unroll
    for (int kt = 0; kt < 4; ++kt) {
        const bf16x8* Bu = (const bf16x8*)(lds_n + (kt * 4) * 512);
        const bf16x8* Bv = (const bf16x8*)(lds_n + ((kt + 4) * 4) * 512);
#pragma unroll
        for (int cc = 0; cc < 4; ++cc) {
            au[cc] = __builtin_amdgcn_mfma_f32_16x16x32_bf16(a[kt], Bu[cc * 64 + lane], au[cc], 0, 0, 0);
            av[cc] = __builtin_amdgcn_mfma_f32_16x16x32_bf16(a[kt], Bv[cc * 64 + lane], av[cc], 0, 0, 0);
        }
    }

    int ntv[4];
#pragma unroll
    for (int i = 0; i < 4; ++i) {
        int nn = tile + 4 * g + i;
        ntv[i] = ntype[nn < NN ? nn : NN - 1];
    }
    const unsigned short* ohu = (const unsigned short*)((const char*)ws + OHU_OFF);
    const unsigned short* ohv = (const unsigned short*)((const char*)ws + OHV_OFF);
    unsigned short* uT = (unsigned short*)((char*)ws + U_OFF);
    unsigned short* vT = (unsigned short*)((char*)ws + V_OFF);
    short* tb = lds_n + 16384 + wave * 1024;
    int nst = tile + m;

    // ---- u: transpose via per-wave swizzled LDS buffer, coalesced store
#pragma unroll
    for (int cc = 0; cc < 4; ++cc)
#pragma unroll
        for (int i = 0; i < 4; ++i) {
            float val = au[cc][i] + bf2f((short)ohu[ntv[i] * 64 + 16 * cc + m]);
            int r16 = 4 * g + i;
            tb[(r16 * 64 + 16 * cc + m) ^ ((r16 & 7) << 3)] = f2bf(val);
        }
    if (nst < NN) {
#pragma unroll
        for (int s2 = 0; s2 < 2; ++s2) {
            int idx = (m * 64 + 16 * g + 8 * s2) ^ ((m & 7) << 3);
            *(bf16x8*)(uT + (size_t)nst * 64 + 16 * g + 8 * s2) = *(const bf16x8*)(tb + idx);
        }
    }
    // ---- v (same buffer; same-wave WAR/RAW ordered by lgkmcnt)
#pragma unroll
    for (int cc = 0; cc < 4; ++cc)
#pragma unroll
        for (int i = 0; i < 4; ++i) {
            float val = av[cc][i] + bf2f((short)ohv[ntv[i] * 64 + 16 * cc + m]);
            int r16 = 4 * g + i;
            tb[(r16 * 64 + 16 * cc + m) ^ ((r16 & 7) << 3)] = f2bf(val);
        }
    if (nst < NN) {
#pragma unroll
        for (int s2 = 0; s2 < 2; ++s2) {
            int idx = (m * 64 + 16 * g + 8 * s2) ^ ((m & 7) << 3);
            *(bf16x8*)(vT + (size_t)nst * 64 + 16 * g + 8 * s2) = *(const bf16x8*)(tb + idx);
        }
    }
}

__global__ __launch_bounds__(512) void edge_kernel(
    const int* __restrict__ ei,
    const int* __restrict__ etype,
    const float* __restrict__ ws,
    const float* __restrict__ b2,
    float* __restrict__ out) {
    // LDS: B2frag [0,1024) shorts | et_tab [1024,2048) shorts
    __shared__ __align__(16) short lds_e[2048];
    int tid = threadIdx.x;
    if (tid < 128)
        ((float4*)lds_e)[tid] = *(const float4*)((const char*)ws + B2F_OFF + tid * 16);
    else if (tid < 256)
        ((float4*)lds_e)[tid] = *(const float4*)((const char*)ws + ETT_OFF + (tid - 128) * 16);
    __syncthreads();

    int wave = tid >> 6, lane = tid & 63, m = lane & 15, g = lane >> 4;
    int tile = blockIdx.x * 128 + wave * 16;
    int e = tile + m;

    int row = ei[e];
    int col = ei[NE + e];
    int et = etype[e];

    // issue all gathers
    const float2* SQ = (const float2*)((const char*)ws + SQ_OFF);
    float2 sqr = SQ[row], sqc = SQ[col];
    const unsigned short* uT = (const unsigned short*)((const char*)ws + U_OFF);
    const unsigned short* vT = (const unsigned short*)((const char*)ws + V_OFF);
    bf16x8 U0 = *(const bf16x8*)(uT + (size_t)row * 64 + 8 * g);
    bf16x8 U1 = *(const bf16x8*)(uT + (size_t)row * 64 + 32 + 8 * g);
    bf16x8 V0 = *(const bf16x8*)(vT + (size_t)col * 64 + 8 * g);
    bf16x8 V1 = *(const bf16x8*)(vT + (size_t)col * 64 + 32 + 8 * g);
    const short* ett = lds_e + 1024;
    bf16x8 T0 = *(const bf16x8*)(ett + et * 64 + ((g ^ (et & 7)) << 3));
    bf16x8 T1 = *(const bf16x8*)(ett + et * 64 + (((4 + g) ^ (et & 7)) << 3));

    float mu = (sqr.x + sqc.x + 3.0f) * (1.0f / TIN);
    float var = (sqr.y + sqc.y + 3.0f) * (1.0f / TIN) - mu * mu;
    float rstd = rsqrtf(var + LN_EPS);

    const float* sst = ws;        // s[64]
    const float* cct = ws + 64;   // c[64]
    bf16x8 af0, af1;
    {
        f32x4 sA = *(const f32x4*)(sst + 8 * g);
        f32x4 sB = *(const f32x4*)(sst + 8 * g + 4);
        f32x4 cA = *(const f32x4*)(cct + 8 * g);
        f32x4 cB = *(const f32x4*)(cct + 8 * g + 4);
#pragma unroll
        for (int j = 0; j < 8; ++j) {
            float t = bf2f(U0[j]) + bf2f(V0[j]) + bf2f(T0[j]);
            float sv = (j < 4) ? sA[j] : sB[j - 4];
            float cv = (j < 4) ? cA[j] : cB[j - 4];
            float h = rstd * (t - mu * sv) + cv;
            af0[j] = f2bf(fmaxf(h, 0.f));
        }
    }
    {
        f32x4 sA = *(const f32x4*)(sst + 32 + 8 * g);
        f32x4 sB = *(const f32x4*)(sst + 32 + 8 * g + 4);
        f32x4 cA = *(const f32x4*)(cct + 32 + 8 * g);
        f32x4 cB = *(const f32x4*)(cct + 32 + 8 * g + 4);
#pragma unroll
        for (int j = 0; j < 8; ++j) {
            float t = bf2f(U1[j]) + bf2f(V1[j]) + bf2f(T1[j]);
            float sv = (j < 4) ? sA[j] : sB[j - 4];
            float cv = (j < 4) ? cA[j] : cB[j - 4];
            float h = rstd * (t - mu * sv) + cv;
            af1[j] = f2bf(fmaxf(h, 0.f));
        }
    }

    const bf16x8* B2f = (const bf16x8*)lds_e;
    f32x4 o = {0.f, 0.f, 0.f, 0.f};
    o = __builtin_amdgcn_mfma_f32_16x16x32_bf16(af0, B2f[lane], o, 0, 0, 0);
    o = __builtin_amdgcn_mfma_f32_16x16x32_bf16(af1, B2f[64 + lane], o, 0, 0, 0);

    float b2v = b2[m];
    int r4 = m >> 2, c4 = m & 3;
    float diag = (c4 == r4) ? 1.0f : 0.0f;
#pragma unroll
    for (int i = 0; i < 4; ++i) {
        float v = o[i] + b2v;
        float mx = fmaxf(v, __shfl_xor(v, 1));
        mx = fmaxf(mx, __shfl_xor(mx, 2));
        float ev = __expf(v - mx);
        float sd = ev + __shfl_xor(ev, 1);
        sd += __shfl_xor(sd, 2);
        out[(size_t)(tile + 4 * g + i) * 16 + m] = diag - ev / sd;
    }
}

extern "C" void kernel_launch(void* const* d_in, const int* in_sizes, int n_in,
                              void* d_out, int out_size, void* d_ws, size_t ws_size,
                              hipStream_t stream) {
    const float* x     = (const float*)d_in[0];
    const int*   ei    = (const int*)d_in[1];
    const int*   etype = (const int*)d_in[2];
    const int*   ntype = (const int*)d_in[3];
    const float* ln_w  = (const float*)d_in[4];
    const float* ln_b  = (const float*)d_in[5];
    const float* W1    = (const float*)d_in[6];
    const float* b1    = (const float*)d_in[7];
    const float* W2    = (const float*)d_in[8];
    const float* b2    = (const float*)d_in[9];
    float* out = (float*)d_out;
    float* ws  = (float*)d_ws;

    prep_weights<<<32, 256, 0, stream>>>(ln_w, ln_b, W1, b1, W2, ws);
    node_uv<<<(NN + 127) / 128, 512, 0, stream>>>(x, ntype, ws);
    edge_kernel<<<NE / 128, 512, 0, stream>>>(ei, etype, ws, b2, out);
}